// Round 17
// baseline (227.326 us; speedup 1.0000x reference)
//
#include <hip/hip_runtime.h>
#include <cstddef>

#define NB 16
#define NM 512
#define NHID 256
#define NTOPK 32
#define NROWS (NB*NM)
#define NLAYER 4

typedef unsigned short ushort_t;
typedef __attribute__((ext_vector_type(8))) short short8;
typedef __attribute__((ext_vector_type(4))) float f32x4;

// MFMA A-fragment LDS layout with bank-decorrelating XOR (verified rounds 5-16).
#define FRAG_OFF(row, c8) (((c8) >> 2) * 1024 + ((((c8) & 3) << 4) + (((row) & 15) ^ ((c8) >> 2))) * 16)
#define FRAG_RD(ks, lane) ((ks) * 1024 + ((((lane) >> 4) << 4) + (((lane) & 15) ^ (ks))) * 16)

#define MFMA16(a, b, c) __builtin_amdgcn_mfma_f32_16x16x32_bf16((a), (b), (c), 0, 0, 0)

__device__ __forceinline__ float mish_f(float v) {
    if (v > 20.0f) return v;
    float t = __expf(v);
    float u = t * (t + 2.0f);
    return v * (u / (u + 2.0f));
}
__device__ __forceinline__ ushort_t f2b(float f) {   // fp32 -> bf16 RNE
    unsigned u = __float_as_uint(f);
    return (ushort_t)((u + 0x7FFFu + ((u >> 16) & 1u)) >> 16);
}
__device__ __forceinline__ float b2f(ushort_t h) {
    return __uint_as_float(((unsigned)h) << 16);
}

// ---------------- prep: wconv (768 blocks) + topk (2048 blocks) --------------
__global__ __launch_bounds__(256) void prep_kernel(const float* __restrict__ edge,
                                                   int* __restrict__ tidx,
                                                   float* __restrict__ tw,
                                                   const float* __restrict__ attnW,
                                                   const float* __restrict__ ffnW,
                                                   ushort_t* __restrict__ wb) {
    if (blockIdx.x < 768) {
        int t = blockIdx.x * 256 + threadIdx.x;
        int frag = t >> 9, r = t & 511;
        int ks = r >> 6, l = r & 63;
        const float* src;
        if (frag < 256) src = attnW + ((size_t)(frag >> 6) * 1024 + (frag & 63) * 16 + (l & 15)) * 256;
        else { int fi = frag - 256; src = ffnW + ((size_t)(fi >> 5) * 512 + (fi & 31) * 16 + (l & 15)) * 256; }
        src += ks * 32 + (l >> 4) * 8;
        short8 o;
        #pragma unroll
        for (int j = 0; j < 8; ++j) o[j] = (short)f2b(src[j]);
        *(short8*)(wb + (size_t)t * 8) = o;
        return;
    }
    const int lane = threadIdx.x & 63, w = threadIdx.x >> 6;
    const int row = (blockIdx.x - 768) * 4 + w;
    const float* er = edge + (size_t)row * NM;
    float v[8]; unsigned u[8];
    #pragma unroll
    for (int s = 0; s < 8; ++s) { v[s] = er[s * 64 + lane]; u[s] = __float_as_uint(v[s]); }
    unsigned T = 0;
    for (int bit = 31; bit >= 0; --bit) {
        unsigned Tc = T | (1u << bit);
        int c = 0;
        #pragma unroll
        for (int s = 0; s < 8; ++s) c += (int)__popcll(__ballot(u[s] >= Tc));
        if (c >= NTOPK) T = Tc;
    }
    int cgt = 0;
    #pragma unroll
    for (int s = 0; s < 8; ++s) cgt += (int)__popcll(__ballot(u[s] > T));
    const int extra = NTOPK - cgt;
    float psum = 0.f;
    #pragma unroll
    for (int s = 0; s < 8; ++s) psum += (u[s] > T) ? v[s] : 0.f;
    psum += __shfl_xor(psum, 1); psum += __shfl_xor(psum, 2); psum += __shfl_xor(psum, 4);
    psum += __shfl_xor(psum, 8); psum += __shfl_xor(psum, 16); psum += __shfl_xor(psum, 32);
    const float ssum = psum + (float)extra * __uint_as_float(T);
    const float rden = 0.17677669529663687f / (ssum + 1e-5f);
    const unsigned long long lmask = (1ull << lane) - 1ull;
    int base = 0, eqbase = 0;
    #pragma unroll
    for (int s = 0; s < 8; ++s) {
        bool gt = (u[s] > T), eq = (u[s] == T);
        unsigned long long meq = __ballot(eq);
        int eqrank = eqbase + (int)__popcll(meq & lmask);
        bool sel = gt || (eq && eqrank < extra);
        unsigned long long msel = __ballot(sel);
        if (sel) {
            int pos = base + (int)__popcll(msel & lmask);
            tidx[row * NTOPK + pos] = s * 64 + lane;
            tw[row * NTOPK + pos] = v[s] * rden;
        }
        base += (int)__popcll(msel);
        eqbase += (int)__popcll(meq);
    }
}

// ---------------- K1: LN1 + QKV GEMM (layer 0) + V-partials ------------------
__global__ __launch_bounds__(256) void k1_ln_qkv(const float* __restrict__ xin,
                                                 ushort_t* __restrict__ xb,
                                                 ushort_t* __restrict__ qb,
                                                 ushort_t* __restrict__ kvb,
                                                 float* __restrict__ part,
                                                 const ushort_t* __restrict__ wf,
                                                 const float* __restrict__ bias,
                                                 const float* __restrict__ ga,
                                                 const float* __restrict__ gb) {
    __shared__ __align__(16) char af[8192];
    const int tid = threadIdx.x, lane = tid & 63, w = tid >> 6;
    const int bx = blockIdx.x;
    const int wid = (bx & 7) * 64 + (bx >> 3);   // XCD affinity
    const int bm = wid * 16, bb = wid >> 5, blk = wid & 31;
    const int zb = blockIdx.y;
    {
        const int rr = lane >> 4, c16 = (lane & 15) << 4;
        const int ri = (w << 2) + rr;
        const float* xr = xin + (size_t)(bm + ri) * NHID + c16;
        f32x4 v0 = *(const f32x4*)(xr);
        f32x4 v1 = *(const f32x4*)(xr + 4);
        f32x4 v2 = *(const f32x4*)(xr + 8);
        f32x4 v3 = *(const f32x4*)(xr + 12);
        float s = 0.f;
        #pragma unroll
        for (int k = 0; k < 4; ++k) s += v0[k] + v1[k] + v2[k] + v3[k];
        s += __shfl_xor(s, 1); s += __shfl_xor(s, 2); s += __shfl_xor(s, 4); s += __shfl_xor(s, 8);
        float mean = s * (1.0f / NHID);
        float vr = 0.f;
        #pragma unroll
        for (int k = 0; k < 4; ++k) {
            float d0 = v0[k]-mean, d1 = v1[k]-mean, d2 = v2[k]-mean, d3 = v3[k]-mean;
            vr += d0*d0 + d1*d1 + d2*d2 + d3*d3;
        }
        vr += __shfl_xor(vr, 1); vr += __shfl_xor(vr, 2); vr += __shfl_xor(vr, 4); vr += __shfl_xor(vr, 8);
        vr *= (1.0f / (NHID - 1));
        float rs = 1.0f / (sqrtf(vr) + 1e-6f);
        f32x4 g0 = *(const f32x4*)(ga + c16), g1 = *(const f32x4*)(ga + c16 + 4);
        f32x4 g2 = *(const f32x4*)(ga + c16 + 8), g3 = *(const f32x4*)(ga + c16 + 12);
        f32x4 h0 = *(const f32x4*)(gb + c16), h1 = *(const f32x4*)(gb + c16 + 4);
        f32x4 h2 = *(const f32x4*)(gb + c16 + 8), h3 = *(const f32x4*)(gb + c16 + 12);
        f32x4 o0, o1, o2, o3;
        #pragma unroll
        for (int k = 0; k < 4; ++k) {
            o0[k] = g0[k]*(v0[k]-mean)*rs + h0[k];
            o1[k] = g1[k]*(v1[k]-mean)*rs + h1[k];
            o2[k] = g2[k]*(v2[k]-mean)*rs + h2[k];
            o3[k] = g3[k]*(v3[k]-mean)*rs + h3[k];
        }
        short8 p0, p1;
        #pragma unroll
        for (int k = 0; k < 4; ++k) {
            p0[k] = (short)f2b(o0[k]); p0[4+k] = (short)f2b(o1[k]);
            p1[k] = (short)f2b(o2[k]); p1[4+k] = (short)f2b(o3[k]);
        }
        if (zb == 0) {
            ushort_t* xw = xb + (size_t)(bm + ri) * NHID + c16;
            *(short8*)(xw) = p0;
            *(short8*)(xw + 8) = p1;
        }
        int c8 = (lane & 15) * 2;
        *(short8*)(af + FRAG_OFF(ri, c8)) = p0;
        *(short8*)(af + FRAG_OFF(ri, c8 + 1)) = p1;
    }
    __syncthreads();
    short8 a[8];
    #pragma unroll
    for (int ks = 0; ks < 8; ++ks) a[ks] = *(const short8*)(af + FRAG_RD(ks, lane));
    #pragma unroll
    for (int gi = 0; gi < 3; ++gi) {
        const int col0 = (zb * 3 + gi) * 128 + w * 32;
        f32x4 acc0 = {}, acc1 = {};
        const ushort_t* bp0 = wf + ((size_t)((col0 >> 4) * 8) * 64 + lane) * 8;
        const ushort_t* bp1 = bp0 + 4096;
        #pragma unroll
        for (int ks = 0; ks < 8; ++ks) {
            short8 b0 = *(const short8*)(bp0 + ks * 512);
            short8 b1 = *(const short8*)(bp1 + ks * 512);
            acc0 = MFMA16(a[ks], b0, acc0);
            acc1 = MFMA16(a[ks], b1, acc1);
        }
        const int rbase = bm + (lane >> 4) * 4;
        #pragma unroll
        for (int ni = 0; ni < 2; ++ni) {
            int col = col0 + ni * 16 + (lane & 15);
            float bv = bias[col];
            f32x4 A = ni ? acc1 : acc0;
            #pragma unroll
            for (int j = 0; j < 4; ++j) {
                int row = rbase + j;
                float vv = A[j] + bv;
                if (col < 256) qb[(size_t)row * 256 + col] = f2b(vv);
                else kvb[(size_t)row * 512 + (col - 256)] = f2b(vv);
            }
            if (zb == 1 && gi >= 1) {
                float s2 = A[0] + A[1] + A[2] + A[3] + 4.0f * bv;
                s2 += __shfl_xor(s2, 16); s2 += __shfl_xor(s2, 32);
                if (lane < 16)
                    part[((size_t)bb * 32 + blk) * 256 + (col0 + ni * 16 + lane - 512)] = s2;
            }
        }
    }
}

// ---------------- KB: attn + Wo + LN2 + FFN + [LN1' + QKV'] ------------------
// 256 blocks x 512 threads (8 waves), 32 rows/block: weight-panel amortization
// (r12) PLUS 2 resident blocks/CU (64KB LDS) so barrier drains overlap.
template<int LAST>
__global__ __launch_bounds__(512, 4) void kb_layer(ushort_t* __restrict__ xb,
                                                   float* __restrict__ xout,
                                                   ushort_t* __restrict__ qb,
                                                   const ushort_t* __restrict__ kvb_cur,
                                                   ushort_t* __restrict__ kvb_nxt,
                                                   const float* __restrict__ part_cur,
                                                   float* __restrict__ part_nxt,
                                                   const int* __restrict__ tidx,
                                                   const float* __restrict__ tw,
                                                   const int* __restrict__ msk,
                                                   const ushort_t* __restrict__ wfo,
                                                   const ushort_t* __restrict__ wf1,
                                                   const ushort_t* __restrict__ wf2,
                                                   const ushort_t* __restrict__ wqn,
                                                   const float* __restrict__ bo,
                                                   const float* __restrict__ b1,
                                                   const float* __restrict__ b2,
                                                   const float* __restrict__ bqn,
                                                   const float* __restrict__ ga,
                                                   const float* __restrict__ gb) {
    __shared__ __align__(16) float regA[32 * 256];     // 32KB fp32 x2 tile
    __shared__ __align__(16) char regB[16384];         // bf16 A-frags, 2x 16-row
    __shared__ __align__(16) char regC[16384];         // sidx/sws, then h-frag
    const int tid = threadIdx.x, lane = tid & 63, w = tid >> 6;   // 8 waves
    const int wid = (blockIdx.x & 7) * 32 + (blockIdx.x >> 3);    // XCD affinity
    const int R0 = wid * 32, bb = wid >> 4, blk = wid & 15;
    int* sidx = (int*)regC;                 // [1024]
    float* sws = (float*)(regC + 4096);     // [1024]
    float* vsumf = regA;                    // aliased: dead until ph3 writes regA
    // ---- ph1: stage topk (2 passes), vsum reduce
    #pragma unroll
    for (int i = 0; i < 2; ++i) {
        int idx = i * 512 + tid;
        int nb = tidx[(size_t)R0 * NTOPK + idx];
        float wv = tw[(size_t)R0 * NTOPK + idx];
        sidx[idx] = (msk[bb * NM + nb] == 0) ? (nb | (int)0x80000000) : nb;
        sws[idx] = wv;
    }
    if (tid < 256) {
        float s = 0.f;
        #pragma unroll
        for (int p = 0; p < 32; ++p) s += part_cur[((size_t)bb * 32 + p) * 256 + tid];
        vsumf[tid] = s;
    }
    // attention: 16 lanes/row (4 rows/wave); lane covers 16 cols; head = 2-lane pair
    const int rr = w * 4 + (lane >> 4);     // local row 0..31
    const int li = lane & 15;
    const int cbase = li * 16;
    float qv[16];
    {
        const ushort_t* qp = qb + (size_t)(R0 + rr) * 256 + cbase;
        short8 q0 = *(const short8*)(qp);
        short8 q1 = *(const short8*)(qp + 8);
        #pragma unroll
        for (int k = 0; k < 8; ++k) { qv[k] = b2f((ushort_t)q0[k]); qv[8+k] = b2f((ushort_t)q1[k]); }
    }
    __syncthreads();
    // ---- ph2: sparse attention, 32 serial iters, exact per-head (pair) dots
    {
        float accv[16];
        #pragma unroll
        for (int k = 0; k < 16; ++k) accv[k] = 0.f;
        float den = 0.f;
        const ushort_t* kvbase = kvb_cur + (size_t)(bb * NM) * 512 + cbase;
        for (int j = 0; j < NTOPK; ++j) {
            int raw = sidx[rr * 32 + j];
            float swv = sws[rr * 32 + j];
            const ushort_t* kp = kvbase + (size_t)(raw & 511) * 512;
            short8 kA = *(const short8*)(kp);
            short8 kB = *(const short8*)(kp + 8);
            short8 vA = *(const short8*)(kp + 256);
            short8 vB = *(const short8*)(kp + 264);
            float p = 0.f;
            #pragma unroll
            for (int t = 0; t < 8; ++t) p += qv[t] * b2f((ushort_t)kA[t]);
            #pragma unroll
            for (int t = 0; t < 8; ++t) p += qv[8 + t] * b2f((ushort_t)kB[t]);
            p += __shfl_xor(p, 1);          // per-head 32-col dot (2-lane pair)
            float sarg = (raw < 0) ? -1e12f : p;
            float e = __expf(sarg * swv);
            float em1 = e - 1.0f;
            den += em1;
            #pragma unroll
            for (int t = 0; t < 8; ++t) accv[t] += em1 * b2f((ushort_t)vA[t]);
            #pragma unroll
            for (int t = 0; t < 8; ++t) accv[8 + t] += em1 * b2f((ushort_t)vB[t]);
        }
        float rden = 1.0f / (den + 512.0f);   // per-head denominator
        short8 p0, p1;
        #pragma unroll
        for (int t = 0; t < 8; ++t) {
            p0[t] = (short)f2b((accv[t] + vsumf[cbase + t]) * rden);
            p1[t] = (short)f2b((accv[8 + t] + vsumf[cbase + 8 + t]) * rden);
        }
        int c8 = li * 2;
        *(short8*)(regB + (rr >> 4) * 8192 + FRAG_OFF(rr, c8)) = p0;
        *(short8*)(regB + (rr >> 4) * 8192 + FRAG_OFF(rr, c8 + 1)) = p1;
    }
    __syncthreads();
    // ---- ph3: Wo GEMM + mish + residual(xb) -> regA; wave covers ct = w, w+8
    {
        #pragma unroll
        for (int gg = 0; gg < 2; ++gg) {
            const int ct = w + gg * 8;
            short8 b[8];
            const ushort_t* bp = wfo + (size_t)ct * 4096 + (size_t)lane * 8;
            #pragma unroll
            for (int ks = 0; ks < 8; ++ks) b[ks] = *(const short8*)(bp + ks * 512);
            int col = ct * 16 + (lane & 15);
            float bv = bo[col];
            #pragma unroll
            for (int rh = 0; rh < 2; ++rh) {
                f32x4 acc = {};
                #pragma unroll
                for (int ks = 0; ks < 8; ++ks)
                    acc = MFMA16(*(const short8*)(regB + rh * 8192 + FRAG_RD(ks, lane)), b[ks], acc);
                #pragma unroll
                for (int j = 0; j < 4; ++j) {
                    int row = rh * 16 + (lane >> 4) * 4 + j;
                    float res = b2f(xb[(size_t)(R0 + row) * NHID + col]);
                    regA[row * 256 + col] = mish_f(acc[j] + bv) + res;
                }
            }
        }
    }
    __syncthreads();
    // ---- ph4: LN2 on regA (k1-style: 4 rows/wave, 16 lanes x 16 cols) -> regB
    {
        const int c16 = li << 4;
        float* xr = regA + rr * 256 + c16;
        f32x4 v0 = *(const f32x4*)(xr);
        f32x4 v1 = *(const f32x4*)(xr + 4);
        f32x4 v2 = *(const f32x4*)(xr + 8);
        f32x4 v3 = *(const f32x4*)(xr + 12);
        float s = 0.f;
        #pragma unroll
        for (int k = 0; k < 4; ++k) s += v0[k] + v1[k] + v2[k] + v3[k];
        s += __shfl_xor(s, 1); s += __shfl_xor(s, 2); s += __shfl_xor(s, 4); s += __shfl_xor(s, 8);
        float mean = s * (1.0f / NHID);
        float vr = 0.f;
        #pragma unroll
        for (int k = 0; k < 4; ++k) {
            float d0 = v0[k]-mean, d1 = v1[k]-mean, d2 = v2[k]-mean, d3 = v3[k]-mean;
            vr += d0*d0 + d1*d1 + d2*d2 + d3*d3;
        }
        vr += __shfl_xor(vr, 1); vr += __shfl_xor(vr, 2); vr += __shfl_xor(vr, 4); vr += __shfl_xor(vr, 8);
        vr *= (1.0f / (NHID - 1));
        float rs = 1.0f / (sqrtf(vr) + 1e-6f);
        f32x4 g0 = *(const f32x4*)(ga + c16), g1 = *(const f32x4*)(ga + c16 + 4);
        f32x4 g2 = *(const f32x4*)(ga + c16 + 8), g3 = *(const f32x4*)(ga + c16 + 12);
        f32x4 h0 = *(const f32x4*)(gb + c16), h1 = *(const f32x4*)(gb + c16 + 4);
        f32x4 h2 = *(const f32x4*)(gb + c16 + 8), h3 = *(const f32x4*)(gb + c16 + 12);
        f32x4 o0, o1, o2, o3;
        #pragma unroll
        for (int k = 0; k < 4; ++k) {
            o0[k] = g0[k]*(v0[k]-mean)*rs + h0[k];
            o1[k] = g1[k]*(v1[k]-mean)*rs + h1[k];
            o2[k] = g2[k]*(v2[k]-mean)*rs + h2[k];
            o3[k] = g3[k]*(v3[k]-mean)*rs + h3[k];
        }
        *(f32x4*)(xr) = o0; *(f32x4*)(xr + 4) = o1;
        *(f32x4*)(xr + 8) = o2; *(f32x4*)(xr + 12) = o3;
        short8 p0, p1;
        #pragma unroll
        for (int k = 0; k < 4; ++k) {
            p0[k] = (short)f2b(o0[k]); p0[4+k] = (short)f2b(o1[k]);
            p1[k] = (short)f2b(o2[k]); p1[4+k] = (short)f2b(o3[k]);
        }
        int c8 = li * 2;
        *(short8*)(regB + (rr >> 4) * 8192 + FRAG_OFF(rr, c8)) = p0;
        *(short8*)(regB + (rr >> 4) * 8192 + FRAG_OFF(rr, c8 + 1)) = p1;
    }
    __syncthreads();
    // ---- ph5: FFN1 (mish) -> h-frag in regC (sidx/sws dead)
    {
        #pragma unroll
        for (int gg = 0; gg < 2; ++gg) {
            const int ct = w + gg * 8;
            short8 b[8];
            const ushort_t* bp = wf1 + (size_t)ct * 4096 + (size_t)lane * 8;
            #pragma unroll
            for (int ks = 0; ks < 8; ++ks) b[ks] = *(const short8*)(bp + ks * 512);
            int col = ct * 16 + (lane & 15);
            float bv = b1[col];
            int c8 = col >> 3;
            #pragma unroll
            for (int rh = 0; rh < 2; ++rh) {
                f32x4 acc = {};
                #pragma unroll
                for (int ks = 0; ks < 8; ++ks)
                    acc = MFMA16(*(const short8*)(regB + rh * 8192 + FRAG_RD(ks, lane)), b[ks], acc);
                #pragma unroll
                for (int j = 0; j < 4; ++j) {
                    int row = rh * 16 + (lane >> 4) * 4 + j;
                    *(ushort_t*)(regC + rh * 8192 + FRAG_OFF(row, c8) + (col & 7) * 2) = f2b(mish_f(acc[j] + bv));
                }
            }
        }
    }
    __syncthreads();
    // ---- ph6: FFN2 (mish) + residual(regA = LN2-out)
    {
        #pragma unroll
        for (int gg = 0; gg < 2; ++gg) {
            const int ct = w + gg * 8;
            short8 b[8];
            const ushort_t* bp = wf2 + (size_t)ct * 4096 + (size_t)lane * 8;
            #pragma unroll
            for (int ks = 0; ks < 8; ++ks) b[ks] = *(const short8*)(bp + ks * 512);
            int col = ct * 16 + (lane & 15);
            float bv = b2[col];
            #pragma unroll
            for (int rh = 0; rh < 2; ++rh) {
                f32x4 acc = {};
                #pragma unroll
                for (int ks = 0; ks < 8; ++ks)
                    acc = MFMA16(*(const short8*)(regC + rh * 8192 + FRAG_RD(ks, lane)), b[ks], acc);
                #pragma unroll
                for (int j = 0; j < 4; ++j) {
                    int row = rh * 16 + (lane >> 4) * 4 + j;
                    float v = mish_f(acc[j] + bv) + regA[row * 256 + col];
                    if (LAST) xout[(size_t)(R0 + row) * NHID + col] = v;
                    else regA[row * 256 + col] = v;
                }
            }
        }
    }
    if (LAST) return;
    __syncthreads();
    // ---- ph7: LN1 of next layer -> global xb (bf16) + frag -> regB
    {
        const int c16 = li << 4;
        float* xr = regA + rr * 256 + c16;
        f32x4 v0 = *(const f32x4*)(xr);
        f32x4 v1 = *(const f32x4*)(xr + 4);
        f32x4 v2 = *(const f32x4*)(xr + 8);
        f32x4 v3 = *(const f32x4*)(xr + 12);
        float s = 0.f;
        #pragma unroll
        for (int k = 0; k < 4; ++k) s += v0[k] + v1[k] + v2[k] + v3[k];
        s += __shfl_xor(s, 1); s += __shfl_xor(s, 2); s += __shfl_xor(s, 4); s += __shfl_xor(s, 8);
        float mean = s * (1.0f / NHID);
        float vr = 0.f;
        #pragma unroll
        for (int k = 0; k < 4; ++k) {
            float d0 = v0[k]-mean, d1 = v1[k]-mean, d2 = v2[k]-mean, d3 = v3[k]-mean;
            vr += d0*d0 + d1*d1 + d2*d2 + d3*d3;
        }
        vr += __shfl_xor(vr, 1); vr += __shfl_xor(vr, 2); vr += __shfl_xor(vr, 4); vr += __shfl_xor(vr, 8);
        vr *= (1.0f / (NHID - 1));
        float rs = 1.0f / (sqrtf(vr) + 1e-6f);
        f32x4 g0 = *(const f32x4*)(ga + c16), g1 = *(const f32x4*)(ga + c16 + 4);
        f32x4 g2 = *(const f32x4*)(ga + c16 + 8), g3 = *(const f32x4*)(ga + c16 + 12);
        f32x4 h0 = *(const f32x4*)(gb + c16), h1 = *(const f32x4*)(gb + c16 + 4);
        f32x4 h2 = *(const f32x4*)(gb + c16 + 8), h3 = *(const f32x4*)(gb + c16 + 12);
        f32x4 o0, o1, o2, o3;
        #pragma unroll
        for (int k = 0; k < 4; ++k) {
            o0[k] = g0[k]*(v0[k]-mean)*rs + h0[k];
            o1[k] = g1[k]*(v1[k]-mean)*rs + h1[k];
            o2[k] = g2[k]*(v2[k]-mean)*rs + h2[k];
            o3[k] = g3[k]*(v3[k]-mean)*rs + h3[k];
        }
        short8 p0, p1;
        #pragma unroll
        for (int k = 0; k < 4; ++k) {
            p0[k] = (short)f2b(o0[k]); p0[4+k] = (short)f2b(o1[k]);
            p1[k] = (short)f2b(o2[k]); p1[4+k] = (short)f2b(o3[k]);
        }
        ushort_t* xw = xb + (size_t)(R0 + rr) * NHID + c16;
        *(short8*)(xw) = p0;
        *(short8*)(xw + 8) = p1;
        int c8 = li * 2;
        *(short8*)(regB + (rr >> 4) * 8192 + FRAG_OFF(rr, c8)) = p0;
        *(short8*)(regB + (rr >> 4) * 8192 + FRAG_OFF(rr, c8 + 1)) = p1;
    }
    __syncthreads();
    // ---- ph8: QKV GEMM of next layer (+ V-partials); wave covers 6 col-tiles
    {
        #pragma unroll
        for (int gg = 0; gg < 6; ++gg) {
            const int ct = w + gg * 8;
            short8 b[8];
            const ushort_t* bp = wqn + (size_t)ct * 4096 + (size_t)lane * 8;
            #pragma unroll
            for (int ks = 0; ks < 8; ++ks) b[ks] = *(const short8*)(bp + ks * 512);
            int col = ct * 16 + (lane & 15);
            float bv = bqn[col];
            #pragma unroll
            for (int rh = 0; rh < 2; ++rh) {
                f32x4 acc = {};
                #pragma unroll
                for (int ks = 0; ks < 8; ++ks)
                    acc = MFMA16(*(const short8*)(regB + rh * 8192 + FRAG_RD(ks, lane)), b[ks], acc);
                #pragma unroll
                for (int j = 0; j < 4; ++j) {
                    int row = rh * 16 + (lane >> 4) * 4 + j;
                    float vv = acc[j] + bv;
                    if (col < 256) qb[(size_t)(R0 + row) * 256 + col] = f2b(vv);
                    else kvb_nxt[(size_t)(R0 + row) * 512 + (col - 256)] = f2b(vv);
                }
                if (ct >= 32) {   // V columns: 16-row partial per half
                    float s2 = acc[0] + acc[1] + acc[2] + acc[3] + 4.0f * bv;
                    s2 += __shfl_xor(s2, 16); s2 += __shfl_xor(s2, 32);
                    if (lane < 16)
                        part_nxt[((size_t)bb * 32 + blk * 2 + rh) * 256 + (ct * 16 + lane - 512)] = s2;
                }
            }
        }
    }
}

extern "C" void kernel_launch(void* const* d_in, const int* in_sizes, int n_in,
                              void* d_out, int out_size, void* d_ws, size_t ws_size,
                              hipStream_t stream) {
    (void)in_sizes; (void)n_in; (void)out_size; (void)ws_size;
    const float* node  = (const float*)d_in[0];
    const float* edge  = (const float*)d_in[1];
    const int*   msk   = (const int*)d_in[2];
    const float* attnW = (const float*)d_in[3];
    const float* attnB = (const float*)d_in[4];
    const float* ffnW  = (const float*)d_in[5];
    const float* ffnB  = (const float*)d_in[6];
    const float* lna   = (const float*)d_in[7];
    const float* lnb   = (const float*)d_in[8];

    float* x = (float*)d_out;                       // final output [8192,256] fp32
    float* wsf = (float*)d_ws;
    // workspace: 7,864,320 floats = 30 MiB
    ushort_t* qb    = (ushort_t*)wsf;               // [8192,256] bf16
    ushort_t* xb    = (ushort_t*)(wsf + 1048576);   // [8192,256] bf16 (LN1-out carrier)
    ushort_t* kvbA  = (ushort_t*)(wsf + 2097152);   // [8192,512] bf16
    ushort_t* kvbB  = (ushort_t*)(wsf + 4194304);   // [8192,512] bf16
    ushort_t* wb    = (ushort_t*)(wsf + 6291456);   // 1,572,864 bf16 frag weights
    float*    tw    = wsf + 7077888;                // [8192,32]
    int*      tidx  = (int*)(wsf + 7340032);        // [8192,32]
    float*    partA = wsf + 7602176;                // [16,32,256]
    float*    partB = wsf + 7733248;                // [16,32,256]

    prep_kernel<<<2816, 256, 0, stream>>>(edge, tidx, tw, attnW, ffnW, wb);
    k1_ln_qkv<<<dim3(512, 2), 256, 0, stream>>>(node, xb, qb, kvbA, partA,
                                                wb, attnB, lna, lnb);
    for (int l = 0; l < NLAYER; ++l) {
        ushort_t* kv_c = (l & 1) ? kvbB : kvbA;
        ushort_t* kv_n = (l & 1) ? kvbA : kvbB;
        float* pt_c = (l & 1) ? partB : partA;
        float* pt_n = (l & 1) ? partA : partB;
        const ushort_t* wfo = wb + (size_t)(l * 64 + 48) * 4096;
        const ushort_t* wf1 = wb + (size_t)(256 + l * 32) * 4096;
        const ushort_t* wf2 = wb + (size_t)(256 + l * 32 + 16) * 4096;
        const ushort_t* wqn = wb + (size_t)(((l + 1) & 3) * 64) * 4096;
        const float* bo  = attnB + (size_t)l * 1024 + 768;
        const float* b1  = ffnB + (size_t)l * 512;
        const float* b2  = b1 + 256;
        const float* bqn = attnB + (size_t)((l + 1) & 3) * 1024;
        if (l < NLAYER - 1)
            kb_layer<0><<<256, 512, 0, stream>>>(xb, x, qb, kv_c, kv_n, pt_c, pt_n,
                tidx, tw, msk, wfo, wf1, wf2, wqn, bo, b1, b2, bqn, lna, lnb);
        else
            kb_layer<1><<<256, 512, 0, stream>>>(xb, x, qb, kv_c, kv_n, pt_c, pt_n,
                tidx, tw, msk, wfo, wf1, wf2, wqn, bo, b1, b2, bqn, lna, lnb);
    }
}

// Round 18
// 151.451 us; speedup vs baseline: 1.5010x; 1.5010x over previous
//
#include <hip/hip_runtime.h>
#include <cstddef>

#define NB 16
#define NM 512
#define NHID 256
#define NTOPK 32
#define NROWS (NB*NM)
#define NLAYER 4

typedef unsigned short ushort_t;
typedef __attribute__((ext_vector_type(8))) short short8;
typedef __attribute__((ext_vector_type(4))) float f32x4;

// MFMA A-fragment LDS layout with bank-decorrelating XOR (verified rounds 5-15).
#define FRAG_OFF(row, c8) (((c8) >> 2) * 1024 + ((((c8) & 3) << 4) + (((row) & 15) ^ ((c8) >> 2))) * 16)
#define FRAG_RD(ks, lane) ((ks) * 1024 + ((((lane) >> 4) << 4) + (((lane) & 15) ^ (ks))) * 16)

#define MFMA16(a, b, c) __builtin_amdgcn_mfma_f32_16x16x32_bf16((a), (b), (c), 0, 0, 0)

__device__ __forceinline__ float mish_f(float v) {
    if (v > 20.0f) return v;
    float t = __expf(v);
    float u = t * (t + 2.0f);
    return v * (u / (u + 2.0f));
}
__device__ __forceinline__ ushort_t f2b(float f) {   // fp32 -> bf16 RNE
    unsigned u = __float_as_uint(f);
    return (ushort_t)((u + 0x7FFFu + ((u >> 16) & 1u)) >> 16);
}
__device__ __forceinline__ float b2f(ushort_t h) {
    return __uint_as_float(((unsigned)h) << 16);
}

// ---------------- prep: wconv (768 blocks) + topk (2048 blocks) --------------
__global__ __launch_bounds__(256) void prep_kernel(const float* __restrict__ edge,
                                                   int* __restrict__ tidx,
                                                   float* __restrict__ tw,
                                                   const float* __restrict__ attnW,
                                                   const float* __restrict__ ffnW,
                                                   ushort_t* __restrict__ wb) {
    if (blockIdx.x < 768) {
        int t = blockIdx.x * 256 + threadIdx.x;
        int frag = t >> 9, r = t & 511;
        int ks = r >> 6, l = r & 63;
        const float* src;
        if (frag < 256) src = attnW + ((size_t)(frag >> 6) * 1024 + (frag & 63) * 16 + (l & 15)) * 256;
        else { int fi = frag - 256; src = ffnW + ((size_t)(fi >> 5) * 512 + (fi & 31) * 16 + (l & 15)) * 256; }
        src += ks * 32 + (l >> 4) * 8;
        short8 o;
        #pragma unroll
        for (int j = 0; j < 8; ++j) o[j] = (short)f2b(src[j]);
        *(short8*)(wb + (size_t)t * 8) = o;
        return;
    }
    const int lane = threadIdx.x & 63, w = threadIdx.x >> 6;
    const int row = (blockIdx.x - 768) * 4 + w;
    const float* er = edge + (size_t)row * NM;
    float v[8]; unsigned u[8];
    #pragma unroll
    for (int s = 0; s < 8; ++s) { v[s] = er[s * 64 + lane]; u[s] = __float_as_uint(v[s]); }
    unsigned T = 0;
    for (int bit = 31; bit >= 0; --bit) {
        unsigned Tc = T | (1u << bit);
        int c = 0;
        #pragma unroll
        for (int s = 0; s < 8; ++s) c += (int)__popcll(__ballot(u[s] >= Tc));
        if (c >= NTOPK) T = Tc;
    }
    int cgt = 0;
    #pragma unroll
    for (int s = 0; s < 8; ++s) cgt += (int)__popcll(__ballot(u[s] > T));
    const int extra = NTOPK - cgt;
    float psum = 0.f;
    #pragma unroll
    for (int s = 0; s < 8; ++s) psum += (u[s] > T) ? v[s] : 0.f;
    psum += __shfl_xor(psum, 1); psum += __shfl_xor(psum, 2); psum += __shfl_xor(psum, 4);
    psum += __shfl_xor(psum, 8); psum += __shfl_xor(psum, 16); psum += __shfl_xor(psum, 32);
    const float ssum = psum + (float)extra * __uint_as_float(T);
    const float rden = 0.17677669529663687f / (ssum + 1e-5f);
    const unsigned long long lmask = (1ull << lane) - 1ull;
    int base = 0, eqbase = 0;
    #pragma unroll
    for (int s = 0; s < 8; ++s) {
        bool gt = (u[s] > T), eq = (u[s] == T);
        unsigned long long meq = __ballot(eq);
        int eqrank = eqbase + (int)__popcll(meq & lmask);
        bool sel = gt || (eq && eqrank < extra);
        unsigned long long msel = __ballot(sel);
        if (sel) {
            int pos = base + (int)__popcll(msel & lmask);
            tidx[row * NTOPK + pos] = s * 64 + lane;
            tw[row * NTOPK + pos] = v[s] * rden;
        }
        base += (int)__popcll(msel);
        eqbase += (int)__popcll(meq);
    }
}

// ---------------- K1: LN1 + QKV GEMM (layer 0) + V-partials ------------------
__global__ __launch_bounds__(256) void k1_ln_qkv(const float* __restrict__ xin,
                                                 ushort_t* __restrict__ xb,
                                                 ushort_t* __restrict__ qb,
                                                 ushort_t* __restrict__ kvb,
                                                 float* __restrict__ part,
                                                 const ushort_t* __restrict__ wf,
                                                 const float* __restrict__ bias,
                                                 const float* __restrict__ ga,
                                                 const float* __restrict__ gb) {
    __shared__ __align__(16) char af[8192];
    const int tid = threadIdx.x, lane = tid & 63, w = tid >> 6;
    const int bx = blockIdx.x;
    const int wid = (bx & 7) * 64 + (bx >> 3);   // XCD affinity
    const int bm = wid * 16, bb = wid >> 5, blk = wid & 31;
    const int zb = blockIdx.y;
    {
        const int rr = lane >> 4, c16 = (lane & 15) << 4;
        const int ri = (w << 2) + rr;
        const float* xr = xin + (size_t)(bm + ri) * NHID + c16;
        f32x4 v0 = *(const f32x4*)(xr);
        f32x4 v1 = *(const f32x4*)(xr + 4);
        f32x4 v2 = *(const f32x4*)(xr + 8);
        f32x4 v3 = *(const f32x4*)(xr + 12);
        float s = 0.f;
        #pragma unroll
        for (int k = 0; k < 4; ++k) s += v0[k] + v1[k] + v2[k] + v3[k];
        s += __shfl_xor(s, 1); s += __shfl_xor(s, 2); s += __shfl_xor(s, 4); s += __shfl_xor(s, 8);
        float mean = s * (1.0f / NHID);
        float vr = 0.f;
        #pragma unroll
        for (int k = 0; k < 4; ++k) {
            float d0 = v0[k]-mean, d1 = v1[k]-mean, d2 = v2[k]-mean, d3 = v3[k]-mean;
            vr += d0*d0 + d1*d1 + d2*d2 + d3*d3;
        }
        vr += __shfl_xor(vr, 1); vr += __shfl_xor(vr, 2); vr += __shfl_xor(vr, 4); vr += __shfl_xor(vr, 8);
        vr *= (1.0f / (NHID - 1));
        float rs = 1.0f / (sqrtf(vr) + 1e-6f);
        f32x4 g0 = *(const f32x4*)(ga + c16), g1 = *(const f32x4*)(ga + c16 + 4);
        f32x4 g2 = *(const f32x4*)(ga + c16 + 8), g3 = *(const f32x4*)(ga + c16 + 12);
        f32x4 h0 = *(const f32x4*)(gb + c16), h1 = *(const f32x4*)(gb + c16 + 4);
        f32x4 h2 = *(const f32x4*)(gb + c16 + 8), h3 = *(const f32x4*)(gb + c16 + 12);
        f32x4 o0, o1, o2, o3;
        #pragma unroll
        for (int k = 0; k < 4; ++k) {
            o0[k] = g0[k]*(v0[k]-mean)*rs + h0[k];
            o1[k] = g1[k]*(v1[k]-mean)*rs + h1[k];
            o2[k] = g2[k]*(v2[k]-mean)*rs + h2[k];
            o3[k] = g3[k]*(v3[k]-mean)*rs + h3[k];
        }
        short8 p0, p1;
        #pragma unroll
        for (int k = 0; k < 4; ++k) {
            p0[k] = (short)f2b(o0[k]); p0[4+k] = (short)f2b(o1[k]);
            p1[k] = (short)f2b(o2[k]); p1[4+k] = (short)f2b(o3[k]);
        }
        if (zb == 0) {
            ushort_t* xw = xb + (size_t)(bm + ri) * NHID + c16;
            *(short8*)(xw) = p0;
            *(short8*)(xw + 8) = p1;
        }
        int c8 = (lane & 15) * 2;
        *(short8*)(af + FRAG_OFF(ri, c8)) = p0;
        *(short8*)(af + FRAG_OFF(ri, c8 + 1)) = p1;
    }
    __syncthreads();
    short8 a[8];
    #pragma unroll
    for (int ks = 0; ks < 8; ++ks) a[ks] = *(const short8*)(af + FRAG_RD(ks, lane));
    #pragma unroll
    for (int gi = 0; gi < 3; ++gi) {
        const int col0 = (zb * 3 + gi) * 128 + w * 32;
        f32x4 acc0 = {}, acc1 = {};
        const ushort_t* bp0 = wf + ((size_t)((col0 >> 4) * 8) * 64 + lane) * 8;
        const ushort_t* bp1 = bp0 + 4096;
        #pragma unroll
        for (int ks = 0; ks < 8; ++ks) {
            short8 b0 = *(const short8*)(bp0 + ks * 512);
            short8 b1 = *(const short8*)(bp1 + ks * 512);
            acc0 = MFMA16(a[ks], b0, acc0);
            acc1 = MFMA16(a[ks], b1, acc1);
        }
        const int rbase = bm + (lane >> 4) * 4;
        #pragma unroll
        for (int ni = 0; ni < 2; ++ni) {
            int col = col0 + ni * 16 + (lane & 15);
            float bv = bias[col];
            f32x4 A = ni ? acc1 : acc0;
            #pragma unroll
            for (int j = 0; j < 4; ++j) {
                int row = rbase + j;
                float vv = A[j] + bv;
                if (col < 256) qb[(size_t)row * 256 + col] = f2b(vv);
                else kvb[(size_t)row * 512 + (col - 256)] = f2b(vv);
            }
            if (zb == 1 && gi >= 1) {
                float s2 = A[0] + A[1] + A[2] + A[3] + 4.0f * bv;
                s2 += __shfl_xor(s2, 16); s2 += __shfl_xor(s2, 32);
                if (lane < 16)
                    part[((size_t)bb * 32 + blk) * 256 + (col0 + ni * 16 + lane - 512)] = s2;
            }
        }
    }
}

// ---------------- KB: attn + Wo + LN2 + FFN + [LN1' + QKV'] ------------------
// 256 blocks x 1024 threads, 32 rows/block; weight panels register-prefetched
// one phase early so their L2/L3 latency hides under the previous phase.
template<int LAST>
__global__ __launch_bounds__(1024, 4) void kb_layer(ushort_t* __restrict__ xb,
                                                    float* __restrict__ xout,
                                                    ushort_t* __restrict__ qb,
                                                    const ushort_t* __restrict__ kvb_cur,
                                                    ushort_t* __restrict__ kvb_nxt,
                                                    const float* __restrict__ part_cur,
                                                    float* __restrict__ part_nxt,
                                                    const int* __restrict__ tidx,
                                                    const float* __restrict__ tw,
                                                    const int* __restrict__ msk,
                                                    const ushort_t* __restrict__ wfo,
                                                    const ushort_t* __restrict__ wf1,
                                                    const ushort_t* __restrict__ wf2,
                                                    const ushort_t* __restrict__ wqn,
                                                    const float* __restrict__ bo,
                                                    const float* __restrict__ b1,
                                                    const float* __restrict__ b2,
                                                    const float* __restrict__ bqn,
                                                    const float* __restrict__ ga,
                                                    const float* __restrict__ gb) {
    __shared__ __align__(16) float regA[32 * 256];     // 32KB fp32 x2 tile (stride 256)
    __shared__ __align__(16) char regB[16384];         // bf16 A-frags, 2x 16-row blocks
    __shared__ __align__(16) char regC[16384];         // sidx/sws, then h-frag
    const int tid = threadIdx.x, lane = tid & 63, w = tid >> 6;   // 16 waves
    const int wid = (blockIdx.x & 7) * 32 + (blockIdx.x >> 3);    // XCD affinity
    const int R0 = wid * 32, bb = wid >> 4, blk = wid & 15;
    int* sidx = (int*)regC;                 // [1024]
    float* sws = (float*)(regC + 4096);     // [1024]
    float* vsumf = regA;                    // aliased: dead until ph3 writes regA
    // ---- ph1: stage topk, vsum reduce, residual prefetch (bf16), q load
    {
        int nb = tidx[(size_t)R0 * NTOPK + tid];
        float wv = tw[(size_t)R0 * NTOPK + tid];
        sidx[tid] = (msk[bb * NM + nb] == 0) ? (nb | (int)0x80000000) : nb;
        sws[tid] = wv;
    }
    if (tid < 256) {
        float s = 0.f;
        #pragma unroll
        for (int p = 0; p < 32; ++p) s += part_cur[((size_t)bb * 32 + p) * 256 + tid];
        vsumf[tid] = s;
    }
    float xres[2][4];    // ph3 residual: row=rh*16+(lane>>4)*4+j, col=w*16+(lane&15)
    #pragma unroll
    for (int rh = 0; rh < 2; ++rh)
        #pragma unroll
        for (int j = 0; j < 4; ++j)
            xres[rh][j] = b2f(xb[(size_t)(R0 + rh * 16 + (lane >> 4) * 4 + j) * NHID + w * 16 + (lane & 15)]);
    // attention: wave = 2 rows (lane halves); 32 lanes x 8 cols; head = 4-lane quad
    const int rl = w * 2 + (lane >> 5);     // local row 0..31
    const int cbase = (lane & 31) * 8;
    float qv[8];
    {
        short8 qh = *(const short8*)(qb + (size_t)(R0 + rl) * 256 + cbase);
        #pragma unroll
        for (int k = 0; k < 8; ++k) qv[k] = b2f((ushort_t)qh[k]);
    }
    // prefetch ph3's Wo panel (lands under ph2's attention loop)
    short8 bfo[8];
    {
        const ushort_t* bp = wfo + ((size_t)(w * 8) * 64 + lane) * 8;
        #pragma unroll
        for (int ks = 0; ks < 8; ++ks) bfo[ks] = *(const short8*)(bp + ks * 512);
    }
    __syncthreads();
    // ---- ph2: sparse attention, 32 serial iters, exact per-head (quad) dots
    {
        float accv[8] = {};
        float den = 0.f;
        for (int j = 0; j < NTOPK; ++j) {
            int raw = sidx[rl * 32 + j];
            float swv = sws[rl * 32 + j];
            const ushort_t* kp = kvb_cur + ((size_t)(bb * NM + (raw & 511))) * 512 + cbase;
            short8 kA = *(const short8*)(kp);
            short8 vA = *(const short8*)(kp + 256);
            float p = 0.f;
            #pragma unroll
            for (int t = 0; t < 8; ++t) p += qv[t] * b2f((ushort_t)kA[t]);
            p += __shfl_xor(p, 1); p += __shfl_xor(p, 2);   // per-head 32-col dot
            float sarg = (raw < 0) ? -1e12f : p;
            float e = __expf(sarg * swv);
            float em1 = e - 1.0f;
            den += em1;
            #pragma unroll
            for (int t = 0; t < 8; ++t) accv[t] += em1 * b2f((ushort_t)vA[t]);
        }
        float rden = 1.0f / (den + 512.0f);   // per-head denominator
        short8 p0;
        #pragma unroll
        for (int t = 0; t < 8; ++t) p0[t] = (short)f2b((accv[t] + vsumf[cbase + t]) * rden);
        *(short8*)(regB + (rl >> 4) * 8192 + FRAG_OFF(rl, (lane & 31))) = p0;
    }
    __syncthreads();
    // ---- ph3: Wo GEMM (prefetched panel) + mish + residual -> regA;
    //          prefetch ph5's FFN1 panel under the MFMAs.
    short8 bf1[8];
    {
        const ushort_t* bp = wf1 + ((size_t)(w * 8) * 64 + lane) * 8;
        #pragma unroll
        for (int ks = 0; ks < 8; ++ks) bf1[ks] = *(const short8*)(bp + ks * 512);
        int col = w * 16 + (lane & 15);
        float bv = bo[col];
        #pragma unroll
        for (int rh = 0; rh < 2; ++rh) {
            f32x4 acc = {};
            #pragma unroll
            for (int ks = 0; ks < 8; ++ks)
                acc = MFMA16(*(const short8*)(regB + rh * 8192 + FRAG_RD(ks, lane)), bfo[ks], acc);
            #pragma unroll
            for (int j = 0; j < 4; ++j) {
                int row = rh * 16 + (lane >> 4) * 4 + j;
                regA[row * 256 + col] = mish_f(acc[j] + bv) + xres[rh][j];
            }
        }
    }
    __syncthreads();
    // ---- ph4: LN2 on regA (wave = 2 rows) + frag -> regB
    {
        const int c0 = (lane & 31) * 8;
        float* xr = regA + rl * 256 + c0;
        f32x4 v0 = *(const f32x4*)xr, v1 = *(const f32x4*)(xr + 4);
        float s = v0[0]+v0[1]+v0[2]+v0[3]+v1[0]+v1[1]+v1[2]+v1[3];
        s += __shfl_xor(s,1); s += __shfl_xor(s,2); s += __shfl_xor(s,4);
        s += __shfl_xor(s,8); s += __shfl_xor(s,16);
        float mean = s * (1.0f / NHID);
        float vr = 0.f;
        #pragma unroll
        for (int k = 0; k < 4; ++k) {
            float d0 = v0[k]-mean, d1 = v1[k]-mean;
            vr += d0*d0 + d1*d1;
        }
        vr += __shfl_xor(vr,1); vr += __shfl_xor(vr,2); vr += __shfl_xor(vr,4);
        vr += __shfl_xor(vr,8); vr += __shfl_xor(vr,16);
        vr *= (1.0f / (NHID - 1));
        float rs = 1.0f / (sqrtf(vr) + 1e-6f);
        f32x4 g0 = *(const f32x4*)(ga + c0), g1 = *(const f32x4*)(ga + c0 + 4);
        f32x4 h0 = *(const f32x4*)(gb + c0), h1 = *(const f32x4*)(gb + c0 + 4);
        f32x4 o0, o1;
        #pragma unroll
        for (int k = 0; k < 4; ++k) {
            o0[k] = g0[k]*(v0[k]-mean)*rs + h0[k];
            o1[k] = g1[k]*(v1[k]-mean)*rs + h1[k];
        }
        *(f32x4*)xr = o0; *(f32x4*)(xr + 4) = o1;
        short8 p;
        #pragma unroll
        for (int k = 0; k < 4; ++k) { p[k] = (short)f2b(o0[k]); p[4+k] = (short)f2b(o1[k]); }
        *(short8*)(regB + (rl >> 4) * 8192 + FRAG_OFF(rl, (lane & 31))) = p;
    }
    __syncthreads();
    // ---- ph5: FFN1 (prefetched panel, mish) -> h-frag in regC (sidx/sws dead);
    //          prefetch ph6's FFN2 panel.
    short8 bf2[8];
    {
        const ushort_t* bp = wf2 + ((size_t)(w * 8) * 64 + lane) * 8;
        #pragma unroll
        for (int ks = 0; ks < 8; ++ks) bf2[ks] = *(const short8*)(bp + ks * 512);
        int col = w * 16 + (lane & 15);
        float bv = b1[col];
        int c8 = col >> 3;
        #pragma unroll
        for (int rh = 0; rh < 2; ++rh) {
            f32x4 acc = {};
            #pragma unroll
            for (int ks = 0; ks < 8; ++ks)
                acc = MFMA16(*(const short8*)(regB + rh * 8192 + FRAG_RD(ks, lane)), bf1[ks], acc);
            #pragma unroll
            for (int j = 0; j < 4; ++j) {
                int row = rh * 16 + (lane >> 4) * 4 + j;
                *(ushort_t*)(regC + rh * 8192 + FRAG_OFF(row, c8) + (col & 7) * 2) = f2b(mish_f(acc[j] + bv));
            }
        }
    }
    __syncthreads();
    // ---- ph6: FFN2 (prefetched panel, mish) + residual(regA = LN2-out);
    //          prefetch ph8's first QKV panel (non-LAST only).
    short8 bq0[8];
    {
        if (!LAST) {
            const ushort_t* bp = wqn + (size_t)w * 4096 + (size_t)lane * 8;
            #pragma unroll
            for (int ks = 0; ks < 8; ++ks) bq0[ks] = *(const short8*)(bp + ks * 512);
        }
        int col = w * 16 + (lane & 15);
        float bv = b2[col];
        #pragma unroll
        for (int rh = 0; rh < 2; ++rh) {
            f32x4 acc = {};
            #pragma unroll
            for (int ks = 0; ks < 8; ++ks)
                acc = MFMA16(*(const short8*)(regC + rh * 8192 + FRAG_RD(ks, lane)), bf2[ks], acc);
            #pragma unroll
            for (int j = 0; j < 4; ++j) {
                int row = rh * 16 + (lane >> 4) * 4 + j;
                float v = mish_f(acc[j] + bv) + regA[row * 256 + col];
                if (LAST) xout[(size_t)(R0 + row) * NHID + col] = v;
                else regA[row * 256 + col] = v;
            }
        }
    }
    if (LAST) return;
    __syncthreads();
    // ---- ph7: LN1 of next layer -> global xb (bf16) + frag -> regB
    {
        const int c0 = (lane & 31) * 8;
        float* xr = regA + rl * 256 + c0;
        f32x4 v0 = *(const f32x4*)xr, v1 = *(const f32x4*)(xr + 4);
        float s = v0[0]+v0[1]+v0[2]+v0[3]+v1[0]+v1[1]+v1[2]+v1[3];
        s += __shfl_xor(s,1); s += __shfl_xor(s,2); s += __shfl_xor(s,4);
        s += __shfl_xor(s,8); s += __shfl_xor(s,16);
        float mean = s * (1.0f / NHID);
        float vr = 0.f;
        #pragma unroll
        for (int k = 0; k < 4; ++k) {
            float d0 = v0[k]-mean, d1 = v1[k]-mean;
            vr += d0*d0 + d1*d1;
        }
        vr += __shfl_xor(vr,1); vr += __shfl_xor(vr,2); vr += __shfl_xor(vr,4);
        vr += __shfl_xor(vr,8); vr += __shfl_xor(vr,16);
        vr *= (1.0f / (NHID - 1));
        float rs = 1.0f / (sqrtf(vr) + 1e-6f);
        f32x4 g0 = *(const f32x4*)(ga + c0), g1 = *(const f32x4*)(ga + c0 + 4);
        f32x4 h0 = *(const f32x4*)(gb + c0), h1 = *(const f32x4*)(gb + c0 + 4);
        f32x4 o0, o1;
        #pragma unroll
        for (int k = 0; k < 4; ++k) {
            o0[k] = g0[k]*(v0[k]-mean)*rs + h0[k];
            o1[k] = g1[k]*(v1[k]-mean)*rs + h1[k];
        }
        short8 p;
        #pragma unroll
        for (int k = 0; k < 4; ++k) { p[k] = (short)f2b(o0[k]); p[4+k] = (short)f2b(o1[k]); }
        *(short8*)(xb + (size_t)(R0 + rl) * NHID + c0) = p;
        *(short8*)(regB + (rl >> 4) * 8192 + FRAG_OFF(rl, (lane & 31))) = p;
    }
    __syncthreads();
    // ---- ph8: QKV GEMM of next layer (+ V-partials); gg0 panel prefetched
    {
        #pragma unroll
        for (int gg = 0; gg < 3; ++gg) {
            const int ct = w + gg * 16;
            short8 b[8];
            if (gg == 0) {
                #pragma unroll
                for (int ks = 0; ks < 8; ++ks) b[ks] = bq0[ks];
            } else {
                const ushort_t* bp = wqn + (size_t)ct * 4096 + (size_t)lane * 8;
                #pragma unroll
                for (int ks = 0; ks < 8; ++ks) b[ks] = *(const short8*)(bp + ks * 512);
            }
            int col = ct * 16 + (lane & 15);
            float bv = bqn[col];
            #pragma unroll
            for (int rh = 0; rh < 2; ++rh) {
                f32x4 acc = {};
                #pragma unroll
                for (int ks = 0; ks < 8; ++ks)
                    acc = MFMA16(*(const short8*)(regB + rh * 8192 + FRAG_RD(ks, lane)), b[ks], acc);
                #pragma unroll
                for (int j = 0; j < 4; ++j) {
                    int row = rh * 16 + (lane >> 4) * 4 + j;
                    float vv = acc[j] + bv;
                    if (col < 256) qb[(size_t)(R0 + row) * 256 + col] = f2b(vv);
                    else kvb_nxt[(size_t)(R0 + row) * 512 + (col - 256)] = f2b(vv);
                }
                if (gg == 2) {   // V columns: 16-row partial per half
                    float s2 = acc[0] + acc[1] + acc[2] + acc[3] + 4.0f * bv;
                    s2 += __shfl_xor(s2, 16); s2 += __shfl_xor(s2, 32);
                    if (lane < 16)
                        part_nxt[((size_t)bb * 32 + blk * 2 + rh) * 256 + (ct * 16 + lane - 512)] = s2;
                }
            }
        }
    }
}

extern "C" void kernel_launch(void* const* d_in, const int* in_sizes, int n_in,
                              void* d_out, int out_size, void* d_ws, size_t ws_size,
                              hipStream_t stream) {
    (void)in_sizes; (void)n_in; (void)out_size; (void)ws_size;
    const float* node  = (const float*)d_in[0];
    const float* edge  = (const float*)d_in[1];
    const int*   msk   = (const int*)d_in[2];
    const float* attnW = (const float*)d_in[3];
    const float* attnB = (const float*)d_in[4];
    const float* ffnW  = (const float*)d_in[5];
    const float* ffnB  = (const float*)d_in[6];
    const float* lna   = (const float*)d_in[7];
    const float* lnb   = (const float*)d_in[8];

    float* x = (float*)d_out;                       // final output [8192,256] fp32
    float* wsf = (float*)d_ws;
    // workspace: 7,864,320 floats = 30 MiB
    ushort_t* qb    = (ushort_t*)wsf;               // [8192,256] bf16
    ushort_t* xb    = (ushort_t*)(wsf + 1048576);   // [8192,256] bf16 (LN1-out carrier)
    ushort_t* kvbA  = (ushort_t*)(wsf + 2097152);   // [8192,512] bf16
    ushort_t* kvbB  = (ushort_t*)(wsf + 4194304);   // [8192,512] bf16
    ushort_t* wb    = (ushort_t*)(wsf + 6291456);   // 1,572,864 bf16 frag weights
    float*    tw    = wsf + 7077888;                // [8192,32]
    int*      tidx  = (int*)(wsf + 7340032);        // [8192,32]
    float*    partA = wsf + 7602176;                // [16,32,256]
    float*    partB = wsf + 7733248;                // [16,32,256]

    prep_kernel<<<2816, 256, 0, stream>>>(edge, tidx, tw, attnW, ffnW, wb);
    k1_ln_qkv<<<dim3(512, 2), 256, 0, stream>>>(node, xb, qb, kvbA, partA,
                                                wb, attnB, lna, lnb);
    for (int l = 0; l < NLAYER; ++l) {
        ushort_t* kv_c = (l & 1) ? kvbB : kvbA;
        ushort_t* kv_n = (l & 1) ? kvbA : kvbB;
        float* pt_c = (l & 1) ? partB : partA;
        float* pt_n = (l & 1) ? partA : partB;
        const ushort_t* wfo = wb + (size_t)(l * 64 + 48) * 4096;
        const ushort_t* wf1 = wb + (size_t)(256 + l * 32) * 4096;
        const ushort_t* wf2 = wb + (size_t)(256 + l * 32 + 16) * 4096;
        const ushort_t* wqn = wb + (size_t)(((l + 1) & 3) * 64) * 4096;
        const float* bo  = attnB + (size_t)l * 1024 + 768;
        const float* b1  = ffnB + (size_t)l * 512;
        const float* b2  = b1 + 256;
        const float* bqn = attnB + (size_t)((l + 1) & 3) * 1024;
        if (l < NLAYER - 1)
            kb_layer<0><<<256, 1024, 0, stream>>>(xb, x, qb, kv_c, kv_n, pt_c, pt_n,
                tidx, tw, msk, wfo, wf1, wf2, wqn, bo, b1, b2, bqn, lna, lnb);
        else
            kb_layer<1><<<256, 1024, 0, stream>>>(xb, x, qb, kv_c, kv_n, pt_c, pt_n,
                tidx, tw, msk, wfo, wf1, wf2, wqn, bo, b1, b2, bqn, lna, lnb);
    }
}